// Round 13
// baseline (375.943 us; speedup 1.0000x reference)
//
#include <hip/hip_runtime.h>
#include <hip/hip_cooperative_groups.h>
#include <cmath>

namespace cg = cooperative_groups;

#define NR 65536
#define DIM 512
#define KC 128
#define NPART 8
#define PART_ROWS (NR / NPART)            // 8192 rows per part
#define WAVE_ROWS (PART_ROWS / 4)         // 2048 rows scanned per wave
#define CHUNKS_PER_WAVE (WAVE_ROWS / 64)  // 32 ballot masks per wave
#define LIST_CAP 192                      // mean 64, Poisson sd 8 -> 16 sd

// ---------------------------------------------------------------------------
// Single cooperative kernel: 1024 blocks x 256 threads (4 blocks/CU).
//  Phase A (all 1024 blocks = (class,part)): ballot-scan + compaction +
//           512B-strip gather segment sum (R8-proven structure, 4 waves).
//  grid.sync()
//  Phase B (blocks 0..127): fold 8 part-partials -> r[k]; kappa/logk/ive.
//  grid.sync()
//  Phase C (blocks 0..127): gram row k -> rowsum[k].
//  grid.sync()
//  Phase D (block 0): fold 128 rowsums -> out.
// No atomics anywhere; all fold orders fixed -> bit-deterministic.
// ---------------------------------------------------------------------------
__global__ __launch_bounds__(256, 4) void vmf_all(
    const float* __restrict__ X, const int* __restrict__ y,
    float* __restrict__ partial, int* __restrict__ pcount,
    float* __restrict__ r, float* __restrict__ kappa,
    float* __restrict__ logk, float* __restrict__ bes,
    float* __restrict__ innorm, float* __restrict__ rowsum,
    float* __restrict__ out)
{
    __shared__ unsigned long long masks[4 * CHUNKS_PER_WAVE]; // 1 KB
    __shared__ unsigned short list[LIST_CAP];
    __shared__ int wcnt[4];
    __shared__ float4 sred[4][2][32];                         // 4 KB
    __shared__ float mui[DIM];                                // 2 KB
    __shared__ float wred[4];

    cg::grid_group grid = cg::this_grid();

    const int tid  = threadIdx.x;
    const int lane = tid & 63;
    const int w    = tid >> 6;                 // wave 0..3
    const int k    = blockIdx.x & (KC - 1);    // class
    const int h    = blockIdx.x >> 7;          // part 0..7

    // ================= Phase A: scan + gather =================
    {
        const int wbase = h * PART_ROWS + w * WAVE_ROWS;

        // ---- A1: ballot scan (8 int4 iters per wave) ----
        int cnt = 0;
        #pragma unroll
        for (int it = 0; it < WAVE_ROWS / 256; ++it) {     // 8 iters
            const int4 v = *(const int4*)(y + wbase + it * 256 + lane * 4);
            const unsigned long long m0 = __ballot(v.x == k);
            const unsigned long long m1 = __ballot(v.y == k);
            const unsigned long long m2 = __ballot(v.z == k);
            const unsigned long long m3 = __ballot(v.w == k);
            if (lane == 0) {
                masks[w * CHUNKS_PER_WAVE + it * 4 + 0] = m0;
                masks[w * CHUNKS_PER_WAVE + it * 4 + 1] = m1;
                masks[w * CHUNKS_PER_WAVE + it * 4 + 2] = m2;
                masks[w * CHUNKS_PER_WAVE + it * 4 + 3] = m3;
            }
            cnt += __popcll(m0) + __popcll(m1) + __popcll(m2) + __popcll(m3);
        }
        if (lane == 0) wcnt[w] = cnt;
        __syncthreads();

        int base = 0, ntot = 0;
        #pragma unroll
        for (int w2 = 0; w2 < 4; ++w2) {
            const int c = wcnt[w2];
            if (w2 < w) base += c;
            ntot += c;
        }
        if (ntot > LIST_CAP) ntot = LIST_CAP;  // statistical impossibility guard

        // ---- A2: ordered compaction ----
        {
            int b = base;
            const unsigned long long lt = (1ULL << lane) - 1ULL;
            for (int c = 0; c < CHUNKS_PER_WAVE; ++c) {
                const unsigned long long m = masks[w * CHUNKS_PER_WAVE + c];
                const int pos = b + __popcll(m & lt);
                if (((m >> lane) & 1ULL) && pos < LIST_CAP) {
                    const int it = c >> 2, j = c & 3;
                    list[pos] = (unsigned short)(wbase + it * 256 + lane * 4 + j);
                }
                b += __popcll(m);
            }
        }
        __syncthreads();

        // ---- A3: gather-sum. wave w -> 128-col strip; half-wave row pick ----
        const int pr = lane >> 5;              // half-wave row select
        const int c4 = lane & 31;              // float4 column within strip
        const float* Xs = X + w * 128 + c4 * 4;

        float4 acc[4];
        #pragma unroll
        for (int j = 0; j < 4; ++j) acc[j] = make_float4(0.f, 0.f, 0.f, 0.f);

        int i = 0;
        for (; i + 7 < ntot; i += 8) {         // 8 rows per iter per wave
            int rows[4];
            #pragma unroll
            for (int j = 0; j < 4; ++j) rows[j] = list[i + 2 * j + pr];
            float4 v[4];
            #pragma unroll
            for (int j = 0; j < 4; ++j)
                v[j] = *(const float4*)(Xs + (size_t)rows[j] * DIM);
            #pragma unroll
            for (int j = 0; j < 4; ++j) {
                acc[j].x += v[j].x; acc[j].y += v[j].y;
                acc[j].z += v[j].z; acc[j].w += v[j].w;
            }
        }
        for (; i < ntot; i += 8) {             // predicated tail batch
            #pragma unroll
            for (int j = 0; j < 4; ++j) {
                const int slot = i + 2 * j + pr;
                if (slot < ntot) {
                    const float4 v = *(const float4*)(Xs + (size_t)list[slot] * DIM);
                    acc[j].x += v.x; acc[j].y += v.y;
                    acc[j].z += v.z; acc[j].w += v.w;
                }
            }
        }
        float4 a;
        a.x = (acc[0].x + acc[1].x) + (acc[2].x + acc[3].x);
        a.y = (acc[0].y + acc[1].y) + (acc[2].y + acc[3].y);
        a.z = (acc[0].z + acc[1].z) + (acc[2].z + acc[3].z);
        a.w = (acc[0].w + acc[1].w) + (acc[2].w + acc[3].w);
        sred[w][pr][c4] = a;
        __syncthreads();

        // fold half-waves, write partial[h][k][512] (256 thr x 2 cols)
        const int cs2 = tid >> 6, cc4 = (tid >> 1) & 31, pq = (tid & 1) * 2;
        const float* sA = (const float*)&sred[cs2][0][cc4];
        const float* sB = (const float*)&sred[cs2][1][cc4];
        float2 pv;
        pv.x = sA[pq]     + sB[pq];
        pv.y = sA[pq + 1] + sB[pq + 1];
        *(float2*)&partial[(size_t)(h * KC + k) * DIM + cs2 * 128 + cc4 * 4 + pq] = pv;
        if (tid == 0) pcount[h * KC + k] = ntot;
    }

    grid.sync();

    // ================= Phase B: reduce -> r, kappa, logk, bes, innorm ====
    if (blockIdx.x < KC) {
        const int kb = blockIdx.x;
        float s0 = 0.f, s1 = 0.f;
        #pragma unroll
        for (int hh = 0; hh < NPART; ++hh) {
            const float* p = partial + (size_t)(hh * KC + kb) * DIM;
            s0 += p[tid];
            s1 += p[tid + 256];
        }
        r[(size_t)kb * DIM + tid]       = s0;
        r[(size_t)kb * DIM + tid + 256] = s1;

        float ss = s0 * s0 + s1 * s1;
        for (int off = 32; off; off >>= 1) ss += __shfl_down(ss, off);
        if ((tid & 63) == 0) wred[tid >> 6] = ss;
        __syncthreads();
        if (tid == 0) {
            const float tot = (wred[0] + wred[1]) + (wred[2] + wred[3]);
            const float norm = sqrtf(tot);
            int nki = 0;
            #pragma unroll
            for (int hh = 0; hh < NPART; ++hh) nki += pcount[hh * KC + kb];
            const float nk = (float)nki;
            const float rb = norm / nk;
            float kap = ((float)DIM * rb - rb * rb * rb) / (1.f - rb * rb);
            if (rb > 0.9f) kap = -0.4f + 1.39f * rb + 0.43f / (1.f - rb);
            kappa[kb] = kap;
            logk[kb]  = logf(kap);
            const float v  = 255.5f;
            const float zz = kap / v;
            const float sq = sqrtf(1.f + zz * zz);
            const float tt = 1.f / sq, t2 = tt * tt;
            const float eta = sq + logf(zz / (1.f + sq));
            const float u1 = (3.f * tt - 5.f * tt * t2) / 24.f;
            const float u2 = (81.f * t2 - 462.f * t2 * t2 + 385.f * t2 * t2 * t2) / 1152.f;
            const float u3 = (30375.f * tt * t2 - 369603.f * tt * t2 * t2
                        + 765765.f * tt * t2 * t2 * t2
                        - 425425.f * tt * t2 * t2 * t2 * t2) / 414720.f;
            const float series = 1.f + u1 / v + u2 / (v * v) + u3 / (v * v * v);
            const float ive = expf(v * eta - kap) * series
                        / (sqrtf(2.f * 3.14159265358979f * v) * sqrtf(sq));
            bes[kb] = ive;
            innorm[kb] = 1.f / norm;
        }
    }

    grid.sync();

    // ================= Phase C: gram row -> rowsum =================
    if (blockIdx.x < KC) {
        const int ib = blockIdx.x;
        const float inv_i = innorm[ib];
        mui[tid]       = r[(size_t)ib * DIM + tid]       * inv_i;
        mui[tid + 256] = r[(size_t)ib * DIM + tid + 256] * inv_i;
        __syncthreads();

        float v2 = 0.f;
        if (tid < KC) {
            const float4* rj = (const float4*)(r + (size_t)tid * DIM);
            float acc = 0.f;
            #pragma unroll 4
            for (int d4 = 0; d4 < DIM / 4; ++d4) {
                const float4 v = rj[d4];
                acc += mui[d4 * 4 + 0] * v.x + mui[d4 * 4 + 1] * v.y
                     + mui[d4 * 4 + 2] * v.z + mui[d4 * 4 + 3] * v.w;
            }
            const float dot = acc * innorm[tid];
            const float dstar = 255.5f;
            const float kl = dstar * (logk[tid] - logk[ib]) - kappa[ib]
                           + bes[ib] - bes[tid] + kappa[tid] * dot;
            v2 = kl * kl;
        }
        for (int off = 32; off; off >>= 1) v2 += __shfl_down(v2, off);
        __syncthreads();                       // wred reuse after phase B
        if ((tid & 63) == 0) wred[tid >> 6] = v2;
        __syncthreads();
        if (tid == 0) rowsum[ib] = (wred[0] + wred[1]) + (wred[2] + wred[3]);
    }

    grid.sync();

    // ================= Phase D: final fold =================
    if (blockIdx.x == 0) {
        float v = (tid < KC) ? rowsum[tid] : 0.f;
        for (int off = 32; off; off >>= 1) v += __shfl_down(v, off);
        __syncthreads();
        if ((tid & 63) == 0) wred[tid >> 6] = v;
        __syncthreads();
        if (tid == 0)
            out[0] = ((wred[0] + wred[1]) + (wred[2] + wred[3]))
                     / (float)(KC * KC);
    }
}

extern "C" void kernel_launch(void* const* d_in, const int* in_sizes, int n_in,
                              void* d_out, int out_size, void* d_ws, size_t ws_size,
                              hipStream_t stream)
{
    const float* X = (const float*)d_in[0];
    const int*   y = (const int*)d_in[1];
    float* out = (float*)d_out;
    float* ws  = (float*)d_ws;

    // workspace layout (float units); partial kept clear of the int region
    float* r      = ws;                         // 0      .. 65535
    float* kappa  = ws + 65536;                 // 65536  .. 65663
    float* logk   = ws + 65536 + 128;           // 65664  .. 65791
    float* bes    = ws + 65536 + 256;           // 65792  .. 65919
    float* innorm = ws + 65536 + 384;           // 65920  .. 66047
    float* rowsum = ws + 65536 + 512;           // 66048  .. 66175
    int*   pcount = (int*)(ws + 66176);         // 66176  .. 67199 (1024 ints)
    float* partial = ws + 67584;                // 67584  .. 591871 (8*128*512)

    void* args[] = {
        (void*)&X, (void*)&y, (void*)&partial, (void*)&pcount,
        (void*)&r, (void*)&kappa, (void*)&logk, (void*)&bes,
        (void*)&innorm, (void*)&rowsum, (void*)&out
    };
    hipLaunchCooperativeKernel((const void*)vmf_all,
                               dim3(KC * NPART), dim3(256),
                               args, 0, stream);
}

// Round 14
// 47.663 us; speedup vs baseline: 7.8875x; 7.8875x over previous
//
#include <hip/hip_runtime.h>
#include <cmath>

#define NR 65536
#define DIM 512
#define KC 128
#define NPART 8
#define PART_ROWS (NR / NPART)            // 8192 rows per part
#define WAVE_ROWS (PART_ROWS / 8)         // 1024 rows scanned per wave
#define CHUNKS_PER_WAVE (WAVE_ROWS / 64)  // 16 ballot masks per wave
#define LIST_CAP 192                      // mean 64, Poisson sd 8 -> 16 sd

// ---------------------------------------------------------------------------
// Kernel A: per-(class, part) scan + gather segment sum. No atomics.
// 1024 blocks x 512 threads, 4 blocks/CU. Byte-identical to R8 (best: 47.9us).
// ---------------------------------------------------------------------------
__global__ __launch_bounds__(512, 4) void vmf_scan_sum(
    const float* __restrict__ X, const int* __restrict__ y,
    float* __restrict__ partial, int* __restrict__ pcount)
{
    __shared__ unsigned long long masks[8 * CHUNKS_PER_WAVE]; // 1 KB
    __shared__ unsigned short list[LIST_CAP];
    __shared__ int wcnt[8];
    __shared__ float4 sred[8][2][32];                         // 8 KB

    const int tid  = threadIdx.x;
    const int lane = tid & 63;
    const int w    = tid >> 6;                 // wave 0..7
    const int k    = blockIdx.x & (KC - 1);    // class
    const int h    = blockIdx.x >> 7;          // part 0..7
    const int wbase = h * PART_ROWS + w * WAVE_ROWS;

    // ---- Phase 1: ballot scan (4 unrolled int4 iters) ----
    int cnt = 0;
    #pragma unroll
    for (int it = 0; it < WAVE_ROWS / 256; ++it) {     // 4 iters
        const int4 v = *(const int4*)(y + wbase + it * 256 + lane * 4);
        const unsigned long long m0 = __ballot(v.x == k);
        const unsigned long long m1 = __ballot(v.y == k);
        const unsigned long long m2 = __ballot(v.z == k);
        const unsigned long long m3 = __ballot(v.w == k);
        if (lane == 0) {
            masks[w * CHUNKS_PER_WAVE + it * 4 + 0] = m0;
            masks[w * CHUNKS_PER_WAVE + it * 4 + 1] = m1;
            masks[w * CHUNKS_PER_WAVE + it * 4 + 2] = m2;
            masks[w * CHUNKS_PER_WAVE + it * 4 + 3] = m3;
        }
        cnt += __popcll(m0) + __popcll(m1) + __popcll(m2) + __popcll(m3);
    }
    if (lane == 0) wcnt[w] = cnt;
    __syncthreads();

    int base = 0, ntot = 0;
    #pragma unroll
    for (int w2 = 0; w2 < 8; ++w2) {
        const int c = wcnt[w2];
        if (w2 < w) base += c;
        ntot += c;
    }
    if (ntot > LIST_CAP) ntot = LIST_CAP;      // statistical impossibility guard

    // ---- Phase 2: ordered compaction ----
    {
        int b = base;
        const unsigned long long lt = (1ULL << lane) - 1ULL;
        for (int c = 0; c < CHUNKS_PER_WAVE; ++c) {
            const unsigned long long m = masks[w * CHUNKS_PER_WAVE + c];
            const int pos = b + __popcll(m & lt);
            if (((m >> lane) & 1ULL) && pos < LIST_CAP) {
                const int it = c >> 2, j = c & 3;
                list[pos] = (unsigned short)(wbase + it * 256 + lane * 4 + j);
            }
            b += __popcll(m);
        }
    }
    __syncthreads();

    // ---- Phase 3: gather-sum. wave -> (col-strip cs, parity p) ----
    const int cs = w & 3;                       // float cols [cs*128, +128)
    const int p  = w >> 2;                      // list-slot parity
    const int pr = lane >> 5;                   // half-wave row select
    const int c4 = lane & 31;                   // float4 column within strip
    const float* Xs = X + cs * 128 + c4 * 4;

    float4 acc[4];
    #pragma unroll
    for (int j = 0; j < 4; ++j) acc[j] = make_float4(0.f, 0.f, 0.f, 0.f);

    int i = p;
    for (; i + 14 < ntot; i += 16) {            // 8 rows per iter per wave
        int rows[4];
        #pragma unroll
        for (int j = 0; j < 4; ++j) rows[j] = list[i + 2 * (2 * j + pr)];
        float4 v[4];
        #pragma unroll
        for (int j = 0; j < 4; ++j)
            v[j] = *(const float4*)(Xs + (size_t)rows[j] * DIM);
        #pragma unroll
        for (int j = 0; j < 4; ++j) {
            acc[j].x += v[j].x; acc[j].y += v[j].y;
            acc[j].z += v[j].z; acc[j].w += v[j].w;
        }
    }
    for (; i < ntot; i += 16) {                 // predicated tail batch
        #pragma unroll
        for (int j = 0; j < 4; ++j) {
            const int slot = i + 2 * (2 * j + pr);
            if (slot < ntot) {
                const float4 v = *(const float4*)(Xs + (size_t)list[slot] * DIM);
                acc[j].x += v.x; acc[j].y += v.y;
                acc[j].z += v.z; acc[j].w += v.w;
            }
        }
    }
    float4 a;
    a.x = (acc[0].x + acc[1].x) + (acc[2].x + acc[3].x);
    a.y = (acc[0].y + acc[1].y) + (acc[2].y + acc[3].y);
    a.z = (acc[0].z + acc[1].z) + (acc[2].z + acc[3].z);
    a.w = (acc[0].w + acc[1].w) + (acc[2].w + acc[3].w);
    sred[w][pr][c4] = a;
    __syncthreads();

    const int cs2 = tid >> 7, c2 = tid & 127;
    const int q4 = c2 >> 2, qc = c2 & 3;
    const float* s0 = (const float*)&sred[cs2][0][q4];
    const float* s1 = (const float*)&sred[cs2][1][q4];
    const float* s2 = (const float*)&sred[cs2 + 4][0][q4];
    const float* s3 = (const float*)&sred[cs2 + 4][1][q4];
    partial[(size_t)(h * KC + k) * DIM + cs2 * 128 + c2] =
        (s0[qc] + s1[qc]) + (s2[qc] + s3[qc]);
    if (tid == 0) pcount[h * KC + k] = ntot;
}

// ---------------------------------------------------------------------------
// Kernel B: fold 8 part-partials -> r[K][D]; norm, kappa, logk, ive.
// 128 blocks x 512 threads (thread = column).
// ---------------------------------------------------------------------------
__global__ __launch_bounds__(512) void vmf_reduce2(
    const float* __restrict__ partial, const int* __restrict__ pcount,
    float* __restrict__ r, float* __restrict__ kappa, float* __restrict__ logk,
    float* __restrict__ bes, float* __restrict__ innorm)
{
    const int k = blockIdx.x, t = threadIdx.x;
    float s = 0.f;
    #pragma unroll
    for (int hh = 0; hh < NPART; ++hh)
        s += partial[(size_t)(hh * KC + k) * DIM + t];
    r[(size_t)k * DIM + t] = s;

    float ss = s * s;
    for (int off = 32; off; off >>= 1) ss += __shfl_down(ss, off);
    __shared__ float wsum[8];
    if ((t & 63) == 0) wsum[t >> 6] = ss;
    __syncthreads();
    if (t == 0) {
        float tot = 0.f;
        #pragma unroll
        for (int q = 0; q < 8; ++q) tot += wsum[q];
        const float norm = sqrtf(tot);
        int nki = 0;
        #pragma unroll
        for (int hh = 0; hh < NPART; ++hh) nki += pcount[hh * KC + k];
        const float nk = (float)nki;
        const float rb = norm / nk;
        float kap = ((float)DIM * rb - rb * rb * rb) / (1.f - rb * rb);
        if (rb > 0.9f) kap = -0.4f + 1.39f * rb + 0.43f / (1.f - rb);
        kappa[k] = kap;
        logk[k]  = logf(kap);
        const float v  = 255.5f;
        const float zz = kap / v;
        const float sq = sqrtf(1.f + zz * zz);
        const float tt = 1.f / sq, t2 = tt * tt;
        const float eta = sq + logf(zz / (1.f + sq));
        const float u1 = (3.f * tt - 5.f * tt * t2) / 24.f;
        const float u2 = (81.f * t2 - 462.f * t2 * t2 + 385.f * t2 * t2 * t2) / 1152.f;
        const float u3 = (30375.f * tt * t2 - 369603.f * tt * t2 * t2
                    + 765765.f * tt * t2 * t2 * t2
                    - 425425.f * tt * t2 * t2 * t2 * t2) / 414720.f;
        const float series = 1.f + u1 / v + u2 / (v * v) + u3 / (v * v * v);
        const float ive = expf(v * eta - kap) * series
                    / (sqrtf(2.f * 3.14159265358979f * v) * sqrtf(sq));
        bes[k] = ive;
        innorm[k] = 1.f / norm;
    }
}

// ---------------------------------------------------------------------------
// Kernel C: block i computes kl[i][j]^2 for all j, reduces to rowsum[i].
// ---------------------------------------------------------------------------
__global__ __launch_bounds__(128) void vmf_gram(
    const float* __restrict__ r, const float* __restrict__ kappa,
    const float* __restrict__ logk, const float* __restrict__ bes,
    const float* __restrict__ innorm, float* __restrict__ rowsum)
{
    const int i = blockIdx.x, j = threadIdx.x;
    __shared__ float mui[DIM];
    const float inv_i = innorm[i];
    for (int d = j; d < DIM; d += 128) mui[d] = r[(size_t)i * DIM + d] * inv_i;
    __syncthreads();

    const float4* rj = (const float4*)(r + (size_t)j * DIM);
    float acc = 0.f;
    #pragma unroll 4
    for (int d4 = 0; d4 < DIM / 4; ++d4) {
        float4 v = rj[d4];
        acc += mui[d4 * 4 + 0] * v.x + mui[d4 * 4 + 1] * v.y
             + mui[d4 * 4 + 2] * v.z + mui[d4 * 4 + 3] * v.w;
    }
    const float dot = acc * innorm[j];
    const float dstar = 255.5f;
    float kl = dstar * (logk[j] - logk[i]) - kappa[i] + bes[i] - bes[j]
             + kappa[j] * dot;
    float v2 = kl * kl;
    for (int off = 32; off; off >>= 1) v2 += __shfl_down(v2, off);
    __shared__ float ws2[2];
    if ((j & 63) == 0) ws2[j >> 6] = v2;
    __syncthreads();
    if (j == 0) rowsum[i] = ws2[0] + ws2[1];
}

// ---------------------------------------------------------------------------
// Kernel D: sum 128 row sums -> out[0] = total / K^2
// ---------------------------------------------------------------------------
__global__ __launch_bounds__(128) void vmf_final(
    const float* __restrict__ rowsum, float* __restrict__ out)
{
    const int t = threadIdx.x;
    float v = rowsum[t];
    for (int off = 32; off; off >>= 1) v += __shfl_down(v, off);
    __shared__ float w[2];
    if ((t & 63) == 0) w[t >> 6] = v;
    __syncthreads();
    if (t == 0) out[0] = (w[0] + w[1]) / (float)(KC * KC);
}

extern "C" void kernel_launch(void* const* d_in, const int* in_sizes, int n_in,
                              void* d_out, int out_size, void* d_ws, size_t ws_size,
                              hipStream_t stream)
{
    const float* X = (const float*)d_in[0];
    const int*   y = (const int*)d_in[1];
    float* out = (float*)d_out;
    float* ws  = (float*)d_ws;

    // workspace layout (float units); partial kept clear of the int region
    float* r      = ws;                         // 0      .. 65535
    float* kappa  = ws + 65536;                 // 65536  .. 65663
    float* logk   = ws + 65536 + 128;           // 65664  .. 65791
    float* bes    = ws + 65536 + 256;           // 65792  .. 65919
    float* innorm = ws + 65536 + 384;           // 65920  .. 66047
    float* rowsum = ws + 65536 + 512;           // 66048  .. 66175
    int*   pcount = (int*)(ws + 66176);         // 66176  .. 67199 (1024 ints)
    float* partial = ws + 67584;                // 67584  .. 591871 (8*128*512)

    vmf_scan_sum<<<KC * NPART, 512, 0, stream>>>(X, y, partial, pcount);
    vmf_reduce2<<<KC, 512, 0, stream>>>(partial, pcount, r, kappa, logk, bes,
                                        innorm);
    vmf_gram<<<KC, 128, 0, stream>>>(r, kappa, logk, bes, innorm, rowsum);
    vmf_final<<<1, 128, 0, stream>>>(rowsum, out);
}